// Round 3
// baseline (69.973 us; speedup 1.0000x reference)
//
#include <hip/hip_runtime.h>

#define Bsz 32
#define Nn  1024
#define Ff  128

typedef __attribute__((ext_vector_type(8))) short bf16x8;
typedef __attribute__((ext_vector_type(4))) float f32x4;

// round-to-nearest-even f32 -> bf16 (bit pattern as short)
static __device__ inline short f2bf(float f) {
    unsigned u = __builtin_bit_cast(unsigned, f);
    unsigned r = u + 0x7FFFu + ((u >> 16) & 1u);
    return (short)(r >> 16);
}

// ---------------------------------------------------------------------------
// k0: w f32 [k][g] -> wT bf16 [g][k]  (k-contiguous for MFMA fragments)
// ---------------------------------------------------------------------------
__global__ __launch_bounds__(256) void k0_wt(
    const float* __restrict__ w, short* __restrict__ wT)
{
    int gid = blockIdx.x * blockDim.x + threadIdx.x;
    if (gid < Ff * Ff) {
        int g = gid >> 7, k = gid & 127;
        wT[gid] = f2bf(w[k * Ff + g]);
    }
}

// ---------------------------------------------------------------------------
// k1 (fused prep + gemm1): per 64-row block, each wave owns 16 rows x 128 g.
// Each feats element is loaded exactly once (f32), then: copied to d_out
// tail, converted+stored as bf16 (fb), and used as MFMA A-fragment for
// vw = feats @ w.  wT B-fragments come from global (32 KB, L1-resident).
// ---------------------------------------------------------------------------
__global__ __launch_bounds__(256) void k1_fused(
    const float* __restrict__ feats,
    const short* __restrict__ wT,
    float* __restrict__ out_feats,
    short* __restrict__ fb,
    short* __restrict__ vw)
{
    const int row0 = blockIdx.x * 64;
    const int tid  = threadIdx.x;
    const int wid  = tid >> 6;
    const int lane = tid & 63;
    const int lr = lane & 15;
    const int kg = lane >> 4;

    const int myrow = row0 + wid * 16 + lr;
    const float* frow = feats + (size_t)myrow * Ff;
    float* orow       = out_feats + (size_t)myrow * Ff;
    short* brow       = fb + (size_t)myrow * Ff;

    f32x4 acc[8] = {};

    for (int kc = 0; kc < 4; ++kc) {
        int k0 = kc * 32 + kg * 8;
        float4 v0 = ((const float4*)(frow + k0))[0];
        float4 v1 = ((const float4*)(frow + k0))[1];
        ((float4*)(orow + k0))[0] = v0;
        ((float4*)(orow + k0))[1] = v1;
        bf16x8 a = (bf16x8){ f2bf(v0.x), f2bf(v0.y), f2bf(v0.z), f2bf(v0.w),
                             f2bf(v1.x), f2bf(v1.y), f2bf(v1.z), f2bf(v1.w) };
        *((bf16x8*)(brow + k0)) = a;
        for (int nf = 0; nf < 8; ++nf) {
            bf16x8 b = *((const bf16x8*)(wT + (size_t)(nf * 16 + lr) * Ff + k0));
            acc[nf] = __builtin_amdgcn_mfma_f32_16x16x32_bf16(a, b, acc[nf], 0, 0, 0);
        }
    }

    // C/D layout: col = lane&15, row = (lane>>4)*4 + reg
    for (int nf = 0; nf < 8; ++nf) {
        int g = nf * 16 + lr;
        for (int r = 0; r < 4; ++r)
            vw[(size_t)(row0 + wid * 16 + kg * 4 + r) * Ff + g] = f2bf(acc[nf][r]);
    }
}

// ---------------------------------------------------------------------------
// k2: y[b][i][j] = sum_g vw[b][i][g] * feats_bf[b][j][g] + bias
// grid = 2048 blocks, XCD-swizzled (blk%8 assumed -> XCD) so each XCD owns
// 4 complete batches (panels L2-resident). Block = 128x128 tile, 4 waves
// (2x2), wave = 64x64, 4x4 fragments of 16x16, K=128 in 4 chunks.
//
// SWAPPED-OPERAND epilogue: mfma(b_frag, a_frag, acc) computes the
// transposed tile D[m][n] = sum_g fb[bn0+m][g] * vw[am0+n][g], so with
// C/D layout (col=lane&15, row=(lane>>4)*4+reg) each lane's 4 acc regs are
// ONE y-row (am0+mf*16+lr), FOUR consecutive y-cols (bn0+nf*16+kg*4+r)
// -> one global_store_dwordx4 per fragment per lane. No LDS, no barriers.
// ---------------------------------------------------------------------------
__global__ __launch_bounds__(256) void k2_gemm2(
    const short* __restrict__ vw,     // [B, N, F] bf16
    const short* __restrict__ fb,     // [B, N, F] bf16
    const float* __restrict__ bias,
    float* __restrict__ y)            // [B, N, N]
{
    int blk  = blockIdx.x;
    int xcd  = blk & 7;
    int idx  = blk >> 3;              // 0..255 within XCD
    int bidx = xcd * 4 + (idx >> 6);  // 4 batches per XCD
    int t    = idx & 63;
    int mt = t >> 3, nt = t & 7;

    int tid = threadIdx.x;
    int wid = tid >> 6, lane = tid & 63;
    int wm = wid >> 1, wn = wid & 1;
    int lr = lane & 15, kg = lane >> 4;

    const short* A  = vw + (size_t)bidx * Nn * Ff;
    const short* Bp = fb + (size_t)bidx * Nn * Ff;
    int am0 = mt * 128 + wm * 64;
    int bn0 = nt * 128 + wn * 64;

    f32x4 acc[4][4] = {};   // [nf][mf] — transposed-tile accumulators

    for (int kc = 0; kc < 4; ++kc) {
        int k0 = kc * 32 + kg * 8;
        bf16x8 a[4], b[4];
        for (int mf = 0; mf < 4; ++mf)
            a[mf] = *((const bf16x8*)(A + (size_t)(am0 + mf * 16 + lr) * Ff + k0));
        for (int nf = 0; nf < 4; ++nf)
            b[nf] = *((const bf16x8*)(Bp + (size_t)(bn0 + nf * 16 + lr) * Ff + k0));
        for (int nf = 0; nf < 4; ++nf)
            for (int mf = 0; mf < 4; ++mf)
                acc[nf][mf] = __builtin_amdgcn_mfma_f32_16x16x32_bf16(
                    b[nf], a[mf], acc[nf][mf], 0, 0, 0);
    }

    float bv = bias[0];
    float* Y = y + (size_t)bidx * Nn * Nn;

    // lane's y-row for fragment column-block mf: am0 + mf*16 + lr
    // lane's y-cols for fragment row-block  nf: bn0 + nf*16 + kg*4 .. +3
    for (int mf = 0; mf < 4; ++mf) {
        float* rowp = Y + (size_t)(am0 + mf * 16 + lr) * Nn + bn0 + kg * 4;
        for (int nf = 0; nf < 4; ++nf) {
            f32x4 v;
            v[0] = acc[nf][mf][0] + bv;
            v[1] = acc[nf][mf][1] + bv;
            v[2] = acc[nf][mf][2] + bv;
            v[3] = acc[nf][mf][3] + bv;
            *((f32x4*)(rowp + nf * 16)) = v;
        }
    }
}

extern "C" void kernel_launch(void* const* d_in, const int* in_sizes, int n_in,
                              void* d_out, int out_size, void* d_ws, size_t ws_size,
                              hipStream_t stream) {
    const float* feats = (const float*)d_in[1];
    const float* w     = (const float*)d_in[2];
    const float* bias  = (const float*)d_in[3];
    float* y = (float*)d_out;
    float* out_feats = y + (size_t)Bsz * Nn * Nn;

    short* vw = (short*)d_ws;
    short* fb = vw + (size_t)Bsz * Nn * Ff;
    short* wT = fb + (size_t)Bsz * Nn * Ff;

    k0_wt<<<64, 256, 0, stream>>>(w, wT);
    k1_fused<<<512, 256, 0, stream>>>(feats, wT, out_feats, fb, vw);
    k2_gemm2<<<2048, 256, 0, stream>>>(vw, fb, bias, y);
}